// Round 5
// baseline (113.762 us; speedup 1.0000x reference)
//
#include <hip/hip_runtime.h>
#include <math.h>

#define NPG  128
#define HID  128
#define KSEL 64
#define NT   512   // 8 waves/block; LDS 80KB -> 2 blocks/CU -> 16 waves/CU
#define HS   132   // HpT row stride in dwords (16B-aligned, 132%32=4 -> conflict-free b128)
#define AS   17    // AdjN row stride in dwords (odd -> spread banks)

typedef __attribute__((ext_vector_type(8))) __bf16 bfrag;   // 8 bf16 = 4 VGPRs
typedef __attribute__((ext_vector_type(4))) float f4;

static __device__ __forceinline__ __bf16 us2bf(unsigned short u) {
    union { unsigned short s; __bf16 b; } x; x.s = u; return x.b;
}
static __device__ __forceinline__ unsigned short bf2us(__bf16 b) {
    union { unsigned short s; __bf16 b; } x; x.b = b; return x.s;
}

// Pre-kernel: split W1 (fp32 128x128) into bf16 hi/lo MFMA B-fragments in d_ws.
// Fragment (ks,ct): lane holds B[k=ks*32+quad*8+j][n=ct*16+(lane&15)], quad=lane>>4.
__global__ __launch_bounds__(64) void wsplit_kernel(const float* __restrict__ W1,
                                                    bfrag* __restrict__ whi,
                                                    bfrag* __restrict__ wlo)
{
    const int b = blockIdx.x;          // b = ks*8 + ct
    const int ks = b >> 3, ct = b & 7;
    const int lane = threadIdx.x;
    const int n = lane & 15, quad = lane >> 4;
    bfrag h, l;
#pragma unroll
    for (int j = 0; j < 8; ++j) {
        const int k = ks * 32 + quad * 8 + j;
        float w = W1[k * HID + ct * 16 + n];
        __bf16 hh = (__bf16)w;
        h[j] = hh;
        l[j] = (__bf16)(w - (float)hh);
    }
    whi[b * 64 + lane] = h;
    wlo[b * 64 + lane] = l;
}

__global__ __launch_bounds__(NT, 4) void sagpool_fused(
    const float* __restrict__ x,
    const int*   __restrict__ esrc,
    const int*   __restrict__ edst,
    const bfrag* __restrict__ whi,
    const bfrag* __restrict__ wlo,
    const float* __restrict__ b1,
    const float* __restrict__ Ws,
    const float* __restrict__ bsp,
    const float* __restrict__ Wlin,
    const float* __restrict__ blin,
    float* __restrict__ out,
    int epg)
{
    // 80384 B LDS -> 2 blocks/CU (16 waves/CU)
    __shared__ __align__(16) unsigned HpT[HID * HS];   // H0' hi|lo packed, [feat][node]
    __shared__ __align__(16) unsigned AdjN[NPG * AS];  // nibble counts of Adj+I, [dst][src]
    __shared__ __align__(16) float rsl[NPG];
    __shared__ __align__(16) float spl[NPG];
    __shared__ __align__(16) float scl[NPG];           // scores; reused as pooled
    __shared__ __align__(16) float wgt[NPG];
    __shared__ __align__(16) float pp[4 * HID];

    const int g = blockIdx.x, t = threadIdx.x;
    const int node0 = g * NPG;
    const long e0 = (long)g * epg;
    const int lane = t & 63, wv = t >> 6;         // wv in [0,8)
    const int n16 = lane & 15, quad = lane >> 4;
    const int m0 = wv * 16;                       // this wave's 16-row tile

    // ---- early global loads (edges, x A-frag row, small vectors) ----
    int es[4], ed[4];
#pragma unroll
    for (int i = 0; i < 4; ++i) {
        int e = i * NT + t;
        es[i] = esrc[e0 + e] - node0;
        ed[i] = edst[e0 + e] - node0;
    }
    // x row (m0+n16), split hi/lo into A-frags immediately
    bfrag ah[4], al[4];
    {
        const float* xr0 = x + (long)(node0 + m0 + n16) * HID + quad * 8;
#pragma unroll
        for (int ks = 0; ks < 4; ++ks) {
            float4 a = *reinterpret_cast<const float4*>(xr0 + ks * 32);
            float4 b = *reinterpret_cast<const float4*>(xr0 + ks * 32 + 4);
            float vv[8] = {a.x, a.y, a.z, a.w, b.x, b.y, b.z, b.w};
#pragma unroll
            for (int j = 0; j < 8; ++j) {
                __bf16 hb = (__bf16)vv[j];
                ah[ks][j] = hb;
                al[ks][j] = (__bf16)(vv[j] - (float)hb);
            }
        }
    }
    float b1v[8], wsv[8];
#pragma unroll
    for (int ct = 0; ct < 8; ++ct) {
        b1v[ct] = b1[ct * 16 + n16];
        wsv[ct] = Ws[ct * 16 + n16];
    }
    const float bsv = bsp[0];

    // ---- build Adj+I as nibble counts ----
    for (int i = t; i < NPG * AS; i += NT) AdjN[i] = 0u;
    __syncthreads();
#pragma unroll
    for (int i = 0; i < 4; ++i)
        atomicAdd(&AdjN[ed[i] * AS + (es[i] >> 3)], 1u << ((es[i] & 7) * 4));
    __syncthreads();

    // diagonal +1, then deg+1 = nibble row-sum -> rsqrt
    if (t < NPG) {
        unsigned* row = &AdjN[t * AS];
        row[t >> 3] += 1u << ((t & 7) * 4);
        unsigned sum = 0;
#pragma unroll
        for (int w = 0; w < 16; ++w) {
            unsigned u = row[w];
            unsigned b = (u & 0x0F0F0F0Fu) + ((u >> 4) & 0x0F0F0F0Fu);
            sum += (b * 0x01010101u) >> 24;
        }
        rsl[t] = rsqrtf((float)sum);
    }
    __syncthreads();

    // ---- GEMM1 via MFMA: H0 = (xh+xl)@(wh+wl), rows [m0, m0+16) ----
    f4 acc[8];
#pragma unroll
    for (int ct = 0; ct < 8; ++ct) {
        acc[ct].x = 0.f; acc[ct].y = 0.f; acc[ct].z = 0.f; acc[ct].w = 0.f;
    }
#pragma unroll
    for (int ks = 0; ks < 4; ++ks)
#pragma unroll
        for (int ct = 0; ct < 8; ++ct) {
            bfrag bh = whi[(ks * 8 + ct) * 64 + lane];
            bfrag bl = wlo[(ks * 8 + ct) * 64 + lane];
            acc[ct] = __builtin_amdgcn_mfma_f32_16x16x32_bf16(ah[ks], bh, acc[ct], 0, 0, 0);
            acc[ct] = __builtin_amdgcn_mfma_f32_16x16x32_bf16(al[ks], bh, acc[ct], 0, 0, 0);
            acc[ct] = __builtin_amdgcn_mfma_f32_16x16x32_bf16(ah[ks], bl, acc[ct], 0, 0, 0);
            acc[ct] = __builtin_amdgcn_mfma_f32_16x16x32_bf16(al[ks], bl, acc[ct], 0, 0, 0);
        }

    // epilogue: H0' = rs*H0, pack hi|lo dword, b128 stores feature-major
    {
        const int mb = m0 + quad * 4;
        f4 rs4 = *reinterpret_cast<const f4*>(&rsl[mb]);
#pragma unroll
        for (int ct = 0; ct < 8; ++ct) {
            uint4 st;
            unsigned pw[4];
#pragma unroll
            for (int reg = 0; reg < 4; ++reg) {
                float v = acc[ct][reg] * rs4[reg];
                __bf16 hb = (__bf16)v;
                __bf16 lb = (__bf16)(v - (float)hb);
                pw[reg] = ((unsigned)bf2us(hb) << 16) | (unsigned)bf2us(lb);
            }
            st.x = pw[0]; st.y = pw[1]; st.z = pw[2]; st.w = pw[3];
            *reinterpret_cast<uint4*>(&HpT[(ct * 16 + n16) * HS + mb]) = st;
        }
    }
    __syncthreads();

    // ---- conv1 aggregation via MFMA: agg = (Adj+I) @ H0'(hi+lo) ----
    f4 hacc[8];
#pragma unroll
    for (int ct = 0; ct < 8; ++ct) {
        hacc[ct].x = 0.f; hacc[ct].y = 0.f; hacc[ct].z = 0.f; hacc[ct].w = 0.f;
    }
#pragma unroll
    for (int ks = 0; ks < 4; ++ks) {
        bfrag af;
        {
            unsigned w = AdjN[(m0 + n16) * AS + ks * 4 + quad];
#pragma unroll
            for (int j = 0; j < 8; ++j)
                af[j] = (__bf16)(float)((w >> (4 * j)) & 15u);
        }
#pragma unroll
        for (int ct = 0; ct < 8; ++ct) {
            const unsigned* bp = &HpT[(ct * 16 + n16) * HS + ks * 32 + quad * 8];
            uint4 w0 = *reinterpret_cast<const uint4*>(bp);
            uint4 w1 = *reinterpret_cast<const uint4*>(bp + 4);
            unsigned ww[8] = {w0.x, w0.y, w0.z, w0.w, w1.x, w1.y, w1.z, w1.w};
            bfrag bh, bl;
#pragma unroll
            for (int j = 0; j < 8; ++j) {
                bh[j] = us2bf((unsigned short)(ww[j] >> 16));
                bl[j] = us2bf((unsigned short)(ww[j] & 0xFFFFu));
            }
            hacc[ct] = __builtin_amdgcn_mfma_f32_16x16x32_bf16(af, bh, hacc[ct], 0, 0, 0);
            hacc[ct] = __builtin_amdgcn_mfma_f32_16x16x32_bf16(af, bl, hacc[ct], 0, 0, 0);
        }
    }

    // epilogue in regs: h = relu(rs*agg + b1)   (h stays in registers)
    f4 rsm = *reinterpret_cast<const f4*>(&rsl[m0 + quad * 4]);
#pragma unroll
    for (int ct = 0; ct < 8; ++ct)
#pragma unroll
        for (int reg = 0; reg < 4; ++reg)
            hacc[ct][reg] = fmaxf(hacc[ct][reg] * rsm[reg] + b1v[ct], 0.f);

    // ---- spl' = rs * (h @ Ws): per-row dot, shfl_xor reduce over n-group ----
    {
        float dot[4];
#pragma unroll
        for (int reg = 0; reg < 4; ++reg) dot[reg] = 0.f;
#pragma unroll
        for (int ct = 0; ct < 8; ++ct)
#pragma unroll
            for (int reg = 0; reg < 4; ++reg)
                dot[reg] += hacc[ct][reg] * wsv[ct];
#pragma unroll
        for (int d = 1; d < 16; d <<= 1)
#pragma unroll
            for (int reg = 0; reg < 4; ++reg)
                dot[reg] += __shfl_xor(dot[reg], d, 64);
        if (n16 == 0) {
#pragma unroll
            for (int reg = 0; reg < 4; ++reg)
                spl[m0 + quad * 4 + reg] = rsm[reg] * dot[reg];
        }
    }
    __syncthreads();

    // ---- score = rs * ((Adj+I) @ spl') + bs  via dense nibble rows ----
    if (t < NPG) {
        const unsigned* row = &AdjN[t * AS];
        float sc = 0.f;
#pragma unroll
        for (int w = 0; w < 16; ++w) {
            unsigned u = row[w];
            const float* sp = &spl[w * 8];
            sc += (float)(u & 15u)         * sp[0] + (float)((u >> 4)  & 15u) * sp[1]
                + (float)((u >> 8)  & 15u) * sp[2] + (float)((u >> 12) & 15u) * sp[3]
                + (float)((u >> 16) & 15u) * sp[4] + (float)((u >> 20) & 15u) * sp[5]
                + (float)((u >> 24) & 15u) * sp[6] + (float)(u >> 28)         * sp[7];
        }
        scl[t] = rsl[t] * sc + bsv;
    }
    __syncthreads();

    // ---- top-K by exact rank (stable: lower index wins ties) ----
    if (t < NPG) {
        float v = scl[t];
        int rank = 0;
        for (int j = 0; j < NPG; ++j) {
            float u = scl[j];
            rank += (u > v || (u == v && j < t)) ? 1 : 0;
        }
        wgt[t] = (rank < KSEL) ? tanhf(v) * (1.0f / KSEL) : 0.f;
    }
    __syncthreads();

    // ---- pooled[c] = sum_m wgt[m]*h[m][c] from registers ----
    {
        float p[8];
        f4 wm = *reinterpret_cast<const f4*>(&wgt[m0 + quad * 4]);
#pragma unroll
        for (int ct = 0; ct < 8; ++ct) {
            float s = 0.f;
#pragma unroll
            for (int reg = 0; reg < 4; ++reg)
                s += wm[reg] * hacc[ct][reg];
            p[ct] = s;
        }
#pragma unroll
        for (int d = 16; d < 64; d <<= 1)
#pragma unroll
            for (int ct = 0; ct < 8; ++ct)
                p[ct] += __shfl_xor(p[ct], d, 64);
        // two-step reduction over the 8 waves into pp[4][HID]
        if (wv < 4 && quad == 0) {
#pragma unroll
            for (int ct = 0; ct < 8; ++ct)
                pp[wv * HID + ct * 16 + n16] = p[ct];
        }
        __syncthreads();
        if (wv >= 4 && quad == 0) {
#pragma unroll
            for (int ct = 0; ct < 8; ++ct)
                pp[(wv - 4) * HID + ct * 16 + n16] += p[ct];
        }
    }
    __syncthreads();
    if (t < NPG)
        scl[t] = pp[t] + pp[HID + t] + pp[2 * HID + t] + pp[3 * HID + t];  // pooled
    __syncthreads();

    // ---- out = pooled @ Wlin + blin (split-k over 4 quarters) ----
    {
        const int c = t & 127, hf = t >> 7;
        float s = 0.f;
        for (int k = hf * 32; k < hf * 32 + 32; ++k)
            s += scl[k] * Wlin[k * HID + c];
        pp[t] = s;
    }
    __syncthreads();
    if (t < NPG)
        out[(long)g * HID + t] = pp[t] + pp[t + 128] + pp[t + 256] + pp[t + 384] + blin[t];
}

extern "C" void kernel_launch(void* const* d_in, const int* in_sizes, int n_in,
                              void* d_out, int out_size, void* d_ws, size_t ws_size,
                              hipStream_t stream) {
    const float* x    = (const float*)d_in[0];
    const int*   ei   = (const int*)  d_in[1];
    const float* W1   = (const float*)d_in[3];
    const float* b1   = (const float*)d_in[4];
    const float* Ws   = (const float*)d_in[5];
    const float* bs   = (const float*)d_in[6];
    const float* Wlin = (const float*)d_in[7];
    const float* blin = (const float*)d_in[8];
    float* out = (float*)d_out;

    const int E = in_sizes[1] / 2;          // 1048576
    const int nnodes = in_sizes[0] / HID;   // 65536
    const int B = nnodes / NPG;             // 512
    const int epg = E / B;                  // 2048

    bfrag* whi = reinterpret_cast<bfrag*>(d_ws);       // 32 KB hi frags
    bfrag* wlo = whi + 32 * 64;                        // 32 KB lo frags

    wsplit_kernel<<<32, 64, 0, stream>>>(W1, whi, wlo);
    sagpool_fused<<<B, NT, 0, stream>>>(x, ei, ei + E, whi, wlo, b1, Ws, bs,
                                        Wlin, blin, out, epg);
}

// Round 6
// 113.145 us; speedup vs baseline: 1.0055x; 1.0055x over previous
//
#include <hip/hip_runtime.h>
#include <math.h>

#define NPG  128
#define HID  128
#define KSEL 64
#define NT   256   // 4 waves/block; LDS ~81KB -> 2 blocks/CU
#define HS   132   // HpT row stride in dwords (16B-aligned, conflict-free b128)
#define AS   17    // AdjN row stride in dwords (odd -> spread banks)

typedef __attribute__((ext_vector_type(8))) __bf16 bfrag;   // 8 bf16 = 4 VGPRs
typedef __attribute__((ext_vector_type(4))) float f4;

static __device__ __forceinline__ __bf16 us2bf(unsigned short u) {
    union { unsigned short s; __bf16 b; } x; x.s = u; return x.b;
}
static __device__ __forceinline__ unsigned short bf2us(__bf16 b) {
    union { unsigned short s; __bf16 b; } x; x.b = b; return x.s;
}

// Pre-kernel: split W1 (fp32 128x128) into bf16 hi/lo MFMA B-fragments in d_ws.
// Fragment (ks,ct): lane holds B[k=ks*32+quad*8+j][n=ct*16+(lane&15)], quad=lane>>4.
__global__ __launch_bounds__(64) void wsplit_kernel(const float* __restrict__ W1,
                                                    bfrag* __restrict__ whi,
                                                    bfrag* __restrict__ wlo)
{
    const int b = blockIdx.x;          // b = ks*8 + ct
    const int ks = b >> 3, ct = b & 7;
    const int lane = threadIdx.x;
    const int n = lane & 15, quad = lane >> 4;
    bfrag h, l;
#pragma unroll
    for (int j = 0; j < 8; ++j) {
        const int k = ks * 32 + quad * 8 + j;
        float w = W1[k * HID + ct * 16 + n];
        __bf16 hh = (__bf16)w;
        h[j] = hh;
        l[j] = (__bf16)(w - (float)hh);
    }
    whi[b * 64 + lane] = h;
    wlo[b * 64 + lane] = l;
}

__global__ __launch_bounds__(NT, 2) void sagpool_fused(
    const float* __restrict__ x,
    const int*   __restrict__ esrc,
    const int*   __restrict__ edst,
    const bfrag* __restrict__ whi,
    const bfrag* __restrict__ wlo,
    const float* __restrict__ b1,
    const float* __restrict__ Ws,
    const float* __restrict__ bsp,
    const float* __restrict__ Wlin,
    const float* __restrict__ blin,
    float* __restrict__ out,
    int epg)
{
    // 80,896 B LDS -> 2 blocks/CU
    __shared__ __align__(16) unsigned HpT[HID * HS];   // H0' hi|lo packed; later: Wlin stage
    __shared__ __align__(16) unsigned AdjN[NPG * AS];  // nibble counts of Adj+I, [dst][src]
    __shared__ __align__(16) int   degl[NPG];
    __shared__ __align__(16) float rsl[NPG];
    __shared__ __align__(16) float spl[NPG];
    __shared__ __align__(16) float scl[NPG];           // scores; reused as pooled
    __shared__ __align__(16) float wgt[NPG];
    __shared__ __align__(16) float pp[4 * HID];

    const int g = blockIdx.x, t = threadIdx.x;
    const int node0 = g * NPG;
    const long e0 = (long)g * epg;
    const int lane = t & 63, wv = t >> 6;         // wv in [0,4)
    const int n16 = lane & 15, quad = lane >> 4;
    const int m0 = wv * 32;                       // this wave's 32-row tile

    // ---- early independent global loads: edges, x rows, small vectors ----
    int es[8], ed[8];
#pragma unroll
    for (int i = 0; i < 8; ++i) {
        int e = i * NT + t;
        es[i] = esrc[e0 + e] - node0;
        ed[i] = edst[e0 + e] - node0;
    }
    bfrag ah[8], al[8];   // A-frags for 2 row-tiles x 4 k-slices
    {
        const float* xw = x + (long)(node0 + m0) * HID;
#pragma unroll
        for (int rt = 0; rt < 2; ++rt)
#pragma unroll
            for (int ks = 0; ks < 4; ++ks) {
                const float* xr = xw + (rt * 16 + n16) * HID + ks * 32 + quad * 8;
                float4 a = *reinterpret_cast<const float4*>(xr);
                float4 b = *reinterpret_cast<const float4*>(xr + 4);
                float vv[8] = {a.x, a.y, a.z, a.w, b.x, b.y, b.z, b.w};
                const int r = rt * 4 + ks;
#pragma unroll
                for (int j = 0; j < 8; ++j) {
                    __bf16 hb = (__bf16)vv[j];
                    ah[r][j] = hb;
                    al[r][j] = (__bf16)(vv[j] - (float)hb);
                }
            }
    }
    float b1v[8], wsv[8];
#pragma unroll
    for (int ct = 0; ct < 8; ++ct) {
        b1v[ct] = b1[ct * 16 + n16];
        wsv[ct] = Ws[ct * 16 + n16];
    }
    const float bsv = bsp[0];

    // ---- zero AdjN + degl ----
    for (int i = t; i < NPG * AS; i += NT) AdjN[i] = 0u;
    if (t < NPG) degl[t] = 0;
    __syncthreads();

    // ---- LDS-pipe: build Adj nibbles + degree ----
#pragma unroll
    for (int i = 0; i < 8; ++i) {
        atomicAdd(&AdjN[ed[i] * AS + (es[i] >> 3)], 1u << ((es[i] & 7) * 4));
        atomicAdd(&degl[ed[i]], 1);
    }

    // ---- matrix-pipe (overlaps atomics above): GEMM1 H0 = (xh+xl)@(wh+wl) ----
    f4 acc[2][8];
#pragma unroll
    for (int rt = 0; rt < 2; ++rt)
#pragma unroll
        for (int ct = 0; ct < 8; ++ct) {
            acc[rt][ct].x = 0.f; acc[rt][ct].y = 0.f;
            acc[rt][ct].z = 0.f; acc[rt][ct].w = 0.f;
        }
#pragma unroll
    for (int ks = 0; ks < 4; ++ks)
#pragma unroll
        for (int ct = 0; ct < 8; ++ct) {
            bfrag bh = whi[(ks * 8 + ct) * 64 + lane];
            bfrag bl = wlo[(ks * 8 + ct) * 64 + lane];
#pragma unroll
            for (int rt = 0; rt < 2; ++rt) {
                const int r = rt * 4 + ks;
                acc[rt][ct] = __builtin_amdgcn_mfma_f32_16x16x32_bf16(ah[r], bh, acc[rt][ct], 0, 0, 0);
                acc[rt][ct] = __builtin_amdgcn_mfma_f32_16x16x32_bf16(al[r], bh, acc[rt][ct], 0, 0, 0);
                acc[rt][ct] = __builtin_amdgcn_mfma_f32_16x16x32_bf16(ah[r], bl, acc[rt][ct], 0, 0, 0);
                acc[rt][ct] = __builtin_amdgcn_mfma_f32_16x16x32_bf16(al[r], bl, acc[rt][ct], 0, 0, 0);
            }
        }
    __syncthreads();   // atomics complete

    // ---- rsl from degl; diagonal +1 nibble ----
    if (t < NPG) {
        rsl[t] = rsqrtf((float)(degl[t] + 1));
        AdjN[t * AS + (t >> 3)] += 1u << ((t & 7) * 4);
    }
    __syncthreads();

    // ---- epilogue: H0' = rs*H0, pack hi|lo dword, b128 stores feature-major ----
#pragma unroll
    for (int rt = 0; rt < 2; ++rt) {
        const int mb = m0 + rt * 16 + quad * 4;
        f4 rs4 = *reinterpret_cast<const f4*>(&rsl[mb]);
#pragma unroll
        for (int ct = 0; ct < 8; ++ct) {
            uint4 st;
            unsigned pw[4];
#pragma unroll
            for (int reg = 0; reg < 4; ++reg) {
                float v = acc[rt][ct][reg] * rs4[reg];
                __bf16 hb = (__bf16)v;
                __bf16 lb = (__bf16)(v - (float)hb);
                pw[reg] = ((unsigned)bf2us(hb) << 16) | (unsigned)bf2us(lb);
            }
            st.x = pw[0]; st.y = pw[1]; st.z = pw[2]; st.w = pw[3];
            *reinterpret_cast<uint4*>(&HpT[(ct * 16 + n16) * HS + mb]) = st;
        }
    }
    __syncthreads();

    // ---- conv1 aggregation via MFMA: agg = (Adj+I) @ H0'(hi+lo) ----
    f4 hacc[2][8];
#pragma unroll
    for (int mt = 0; mt < 2; ++mt)
#pragma unroll
        for (int ct = 0; ct < 8; ++ct) {
            hacc[mt][ct].x = 0.f; hacc[mt][ct].y = 0.f;
            hacc[mt][ct].z = 0.f; hacc[mt][ct].w = 0.f;
        }
#pragma unroll
    for (int ks = 0; ks < 4; ++ks) {
        bfrag af[2];
#pragma unroll
        for (int mt = 0; mt < 2; ++mt) {
            unsigned w = AdjN[(m0 + mt * 16 + n16) * AS + ks * 4 + quad];
#pragma unroll
            for (int j = 0; j < 8; ++j)
                af[mt][j] = (__bf16)(float)((w >> (4 * j)) & 15u);
        }
#pragma unroll
        for (int ct = 0; ct < 8; ++ct) {
            const unsigned* bp = &HpT[(ct * 16 + n16) * HS + ks * 32 + quad * 8];
            uint4 w0 = *reinterpret_cast<const uint4*>(bp);
            uint4 w1 = *reinterpret_cast<const uint4*>(bp + 4);
            unsigned ww[8] = {w0.x, w0.y, w0.z, w0.w, w1.x, w1.y, w1.z, w1.w};
            bfrag bh, bl;
#pragma unroll
            for (int j = 0; j < 8; ++j) {
                bh[j] = us2bf((unsigned short)(ww[j] >> 16));
                bl[j] = us2bf((unsigned short)(ww[j] & 0xFFFFu));
            }
#pragma unroll
            for (int mt = 0; mt < 2; ++mt) {
                hacc[mt][ct] = __builtin_amdgcn_mfma_f32_16x16x32_bf16(af[mt], bh, hacc[mt][ct], 0, 0, 0);
                hacc[mt][ct] = __builtin_amdgcn_mfma_f32_16x16x32_bf16(af[mt], bl, hacc[mt][ct], 0, 0, 0);
            }
        }
    }

    // epilogue in regs: h = relu(rs*agg + b1)   (h stays in registers)
    f4 rsm[2];
#pragma unroll
    for (int mt = 0; mt < 2; ++mt)
        rsm[mt] = *reinterpret_cast<const f4*>(&rsl[m0 + mt * 16 + quad * 4]);
#pragma unroll
    for (int mt = 0; mt < 2; ++mt)
#pragma unroll
        for (int ct = 0; ct < 8; ++ct)
#pragma unroll
            for (int reg = 0; reg < 4; ++reg)
                hacc[mt][ct][reg] = fmaxf(hacc[mt][ct][reg] * rsm[mt][reg] + b1v[ct], 0.f);

    // ---- spl' = rs * (h @ Ws): per-row dot, shfl_xor reduce over n-group ----
    {
        float dot[2][4];
#pragma unroll
        for (int mt = 0; mt < 2; ++mt)
#pragma unroll
            for (int reg = 0; reg < 4; ++reg) dot[mt][reg] = 0.f;
#pragma unroll
        for (int ct = 0; ct < 8; ++ct)
#pragma unroll
            for (int mt = 0; mt < 2; ++mt)
#pragma unroll
                for (int reg = 0; reg < 4; ++reg)
                    dot[mt][reg] += hacc[mt][ct][reg] * wsv[ct];
#pragma unroll
        for (int d = 1; d < 16; d <<= 1)
#pragma unroll
            for (int mt = 0; mt < 2; ++mt)
#pragma unroll
                for (int reg = 0; reg < 4; ++reg)
                    dot[mt][reg] += __shfl_xor(dot[mt][reg], d, 64);
        if (n16 == 0) {
#pragma unroll
            for (int mt = 0; mt < 2; ++mt)
#pragma unroll
                for (int reg = 0; reg < 4; ++reg)
                    spl[m0 + mt * 16 + quad * 4 + reg] = rsm[mt][reg] * dot[mt][reg];
        }
    }
    __syncthreads();   // spl ready; ALL HpT reads complete -> HpT region reusable

    // ---- stage Wlin into dead HpT space (consumed 3 barriers later) ----
    {
        float4* WL4 = reinterpret_cast<float4*>(HpT);
        const float4* Wg4 = reinterpret_cast<const float4*>(Wlin);
#pragma unroll
        for (int i = 0; i < 16; ++i)
            WL4[i * NT + t] = Wg4[i * NT + t];
    }

    // ---- score = rs * ((Adj+I) @ spl') + bs  via dense nibble rows ----
    if (t < NPG) {
        const unsigned* row = &AdjN[t * AS];
        float sc = 0.f;
#pragma unroll
        for (int w = 0; w < 16; ++w) {
            unsigned u = row[w];
            const float* sp = &spl[w * 8];
            sc += (float)(u & 15u)         * sp[0] + (float)((u >> 4)  & 15u) * sp[1]
                + (float)((u >> 8)  & 15u) * sp[2] + (float)((u >> 12) & 15u) * sp[3]
                + (float)((u >> 16) & 15u) * sp[4] + (float)((u >> 20) & 15u) * sp[5]
                + (float)((u >> 24) & 15u) * sp[6] + (float)(u >> 28)         * sp[7];
        }
        scl[t] = rsl[t] * sc + bsv;
    }
    __syncthreads();

    // ---- top-K by exact rank (stable), fully unrolled float4 broadcasts ----
    if (t < NPG) {
        float v = scl[t];
        int rank = 0;
#pragma unroll
        for (int j4 = 0; j4 < 32; ++j4) {
            float4 u = *reinterpret_cast<const float4*>(&scl[j4 * 4]);
            const int jb = j4 * 4;
            rank += (u.x > v || (u.x == v && jb     < t)) ? 1 : 0;
            rank += (u.y > v || (u.y == v && jb + 1 < t)) ? 1 : 0;
            rank += (u.z > v || (u.z == v && jb + 2 < t)) ? 1 : 0;
            rank += (u.w > v || (u.w == v && jb + 3 < t)) ? 1 : 0;
        }
        wgt[t] = (rank < KSEL) ? tanhf(v) * (1.0f / KSEL) : 0.f;
    }
    __syncthreads();

    // ---- pooled[c] = sum_m wgt[m]*h[m][c] from registers; shfl over quads ----
    {
        float p[8];
        f4 wm[2];
#pragma unroll
        for (int mt = 0; mt < 2; ++mt)
            wm[mt] = *reinterpret_cast<const f4*>(&wgt[m0 + mt * 16 + quad * 4]);
#pragma unroll
        for (int ct = 0; ct < 8; ++ct) {
            float s = 0.f;
#pragma unroll
            for (int mt = 0; mt < 2; ++mt)
#pragma unroll
                for (int reg = 0; reg < 4; ++reg)
                    s += wm[mt][reg] * hacc[mt][ct][reg];
            p[ct] = s;
        }
#pragma unroll
        for (int d = 16; d < 64; d <<= 1)
#pragma unroll
            for (int ct = 0; ct < 8; ++ct)
                p[ct] += __shfl_xor(p[ct], d, 64);
        if (quad == 0) {
#pragma unroll
            for (int ct = 0; ct < 8; ++ct)
                pp[wv * HID + ct * 16 + n16] = p[ct];
        }
    }
    __syncthreads();
    if (t < NPG)
        scl[t] = pp[t] + pp[HID + t] + pp[2 * HID + t] + pp[3 * HID + t];  // pooled
    __syncthreads();   // also guarantees Wlin LDS stage complete

    // ---- out = pooled @ Wlin (from LDS) + blin, split-k over 2 halves ----
    {
        const int c = t & 127, hf = t >> 7;
        const float* WL = reinterpret_cast<const float*>(HpT);
        float s = 0.f;
#pragma unroll
        for (int k = hf * 64; k < hf * 64 + 64; ++k)
            s += scl[k] * WL[k * HID + c];
        pp[t] = s;
    }
    __syncthreads();
    if (t < NPG)
        out[(long)g * HID + t] = pp[t] + pp[t + 128] + blin[t];
}

extern "C" void kernel_launch(void* const* d_in, const int* in_sizes, int n_in,
                              void* d_out, int out_size, void* d_ws, size_t ws_size,
                              hipStream_t stream) {
    const float* x    = (const float*)d_in[0];
    const int*   ei   = (const int*)  d_in[1];
    const float* W1   = (const float*)d_in[3];
    const float* b1   = (const float*)d_in[4];
    const float* Ws   = (const float*)d_in[5];
    const float* bs   = (const float*)d_in[6];
    const float* Wlin = (const float*)d_in[7];
    const float* blin = (const float*)d_in[8];
    float* out = (float*)d_out;

    const int E = in_sizes[1] / 2;          // 1048576
    const int nnodes = in_sizes[0] / HID;   // 65536
    const int B = nnodes / NPG;             // 512
    const int epg = E / B;                  // 2048

    bfrag* whi = reinterpret_cast<bfrag*>(d_ws);       // 32 KB hi frags
    bfrag* wlo = whi + 32 * 64;                        // 32 KB lo frags

    wsplit_kernel<<<32, 64, 0, stream>>>(W1, whi, wlo);
    sagpool_fused<<<B, NT, 0, stream>>>(x, ei, ei + E, whi, wlo, b1, Ws, bs,
                                        Wlin, blin, out, epg);
}

// Round 7
// 111.671 us; speedup vs baseline: 1.0187x; 1.0132x over previous
//
#include <hip/hip_runtime.h>
#include <math.h>

#define NPG  128
#define HID  128
#define KSEL 64
#define NT   256   // 4 waves/block; LDS 80,384 B -> 2 blocks/CU
#define HS   132   // H0' row stride in dwords (16B-aligned, conflict-free b128)
#define AS   17    // AdjN row stride in dwords (odd -> spread banks)
#define FS   516   // W1 frag-pair stride in dwords (516%32==4 -> spread stage-write banks)

typedef __attribute__((ext_vector_type(8))) __bf16 bfrag;   // 8 bf16 = 4 VGPRs
typedef __attribute__((ext_vector_type(4))) float f4;

static __device__ __forceinline__ __bf16 us2bf(unsigned short u) {
    union { unsigned short s; __bf16 b; } x; x.s = u; return x.b;
}
static __device__ __forceinline__ unsigned short bf2us(__bf16 b) {
    union { unsigned short s; __bf16 b; } x; x.b = b; return x.s;
}

// Single fused kernel, one block per graph.
// LDS phase plan for HpT region (67,584 B):
//   phase A: W1 packed hi|lo bf16 MFMA B-fragments (32 frag-pairs x 516 dwords = 66,048 B)
//   phase B: H0' (rs-scaled x@W1) packed hi|lo, feature-major [feat][node], stride HS
__global__ __launch_bounds__(NT, 2) void sagpool_fused(
    const float* __restrict__ x,
    const int*   __restrict__ esrc,
    const int*   __restrict__ edst,
    const float* __restrict__ W1,
    const float* __restrict__ b1,
    const float* __restrict__ Ws,
    const float* __restrict__ bsp,
    const float* __restrict__ Wlin,
    const float* __restrict__ blin,
    float* __restrict__ out,
    int epg)
{
    __shared__ __align__(16) unsigned HpT[HID * HS];   // 67,584 B (see phase plan)
    __shared__ __align__(16) unsigned AdjN[NPG * AS];  // nibble counts of Adj (+I later)
    __shared__ __align__(16) float rsl[NPG];
    __shared__ __align__(16) float spl[NPG];
    __shared__ __align__(16) float scl[NPG];           // scores; reused as pooled
    __shared__ __align__(16) float wgt[NPG];
    __shared__ __align__(16) float pp[4 * HID];

    const int g = blockIdx.x, t = threadIdx.x;
    const int node0 = g * NPG;
    const long e0 = (long)g * epg;
    const int lane = t & 63, wv = t >> 6;         // wv in [0,4)
    const int n16 = lane & 15, quad = lane >> 4;
    const int m0 = wv * 32;                       // this wave's 32-row tile

    // ---- early independent global loads: edges, x rows, small vectors ----
    int es[8], ed[8];
#pragma unroll
    for (int i = 0; i < 8; ++i) {
        int e = i * NT + t;
        es[i] = esrc[e0 + e] - node0;
        ed[i] = edst[e0 + e] - node0;
    }
    bfrag ah[8], al[8];   // A-frags for 2 row-tiles x 4 k-slices
    {
        const float* xw = x + (long)(node0 + m0) * HID;
#pragma unroll
        for (int rt = 0; rt < 2; ++rt)
#pragma unroll
            for (int ks = 0; ks < 4; ++ks) {
                const float* xr = xw + (rt * 16 + n16) * HID + ks * 32 + quad * 8;
                float4 a = *reinterpret_cast<const float4*>(xr);
                float4 b = *reinterpret_cast<const float4*>(xr + 4);
                float vv[8] = {a.x, a.y, a.z, a.w, b.x, b.y, b.z, b.w};
                const int r = rt * 4 + ks;
#pragma unroll
                for (int j = 0; j < 8; ++j) {
                    __bf16 hb = (__bf16)vv[j];
                    ah[r][j] = hb;
                    al[r][j] = (__bf16)(vv[j] - (float)hb);
                }
            }
    }
    float b1v[8], wsv[8];
#pragma unroll
    for (int ct = 0; ct < 8; ++ct) {
        b1v[ct] = b1[ct * 16 + n16];
        wsv[ct] = Ws[ct * 16 + n16];
    }
    const float bsv = bsp[0];

    // ---- zero AdjN ----
    for (int i = t; i < NPG * AS; i += NT) AdjN[i] = 0u;
    __syncthreads();

    // ---- phase: stage W1 -> LDS frag-pairs (packed hi|lo) + edge nibble atomics ----
    // Fragment (ks,ct): lane holds B[k=ks*32+quad*8+j][n=ct*16+n16], packed hi<<16|lo.
    {
        const float4* W4 = reinterpret_cast<const float4*>(W1);
#pragma unroll
        for (int i = 0; i < 16; ++i) {
            const int fd = i * 256 + t;            // float4 index (coalesced)
            float4 w = W4[fd];
            const int dw = fd * 4;
            const int k = dw >> 7, n = dw & 127;
            const int p = (k >> 5) * 8 + (n >> 4);
            const int lane0 = ((k >> 3) & 3) * 16 + (n & 15);
            const int j = k & 7;
            unsigned* base = &HpT[p * FS + lane0 * 8 + j];
            float vv[4] = {w.x, w.y, w.z, w.w};
#pragma unroll
            for (int e = 0; e < 4; ++e) {
                __bf16 hb = (__bf16)vv[e];
                __bf16 lb = (__bf16)(vv[e] - (float)hb);
                base[e * 8] = ((unsigned)bf2us(hb) << 16) | (unsigned)bf2us(lb);
            }
        }
    }
#pragma unroll
    for (int i = 0; i < 8; ++i)
        atomicAdd(&AdjN[ed[i] * AS + (es[i] >> 3)], 1u << ((es[i] & 7) * 4));
    __syncthreads();   // W1 frags + adjacency complete

    // ---- t<128: deg via nibble row-sum -> rsl; then diagonal +1 (own row) ----
    if (t < NPG) {
        unsigned* row = &AdjN[t * AS];
        unsigned sum = 0;
#pragma unroll
        for (int w = 0; w < 16; ++w) {
            unsigned u = row[w];
            unsigned b = (u & 0x0F0F0F0Fu) + ((u >> 4) & 0x0F0F0F0Fu);
            sum += (b * 0x01010101u) >> 24;
        }
        rsl[t] = rsqrtf((float)(sum + 1));
        row[t >> 3] += 1u << ((t & 7) * 4);
    }

    // ---- GEMM1 via MFMA: H0 = (xh+xl)@(wh+wl), B-frags from LDS ----
    f4 acc[2][8];
#pragma unroll
    for (int rt = 0; rt < 2; ++rt)
#pragma unroll
        for (int ct = 0; ct < 8; ++ct) {
            acc[rt][ct].x = 0.f; acc[rt][ct].y = 0.f;
            acc[rt][ct].z = 0.f; acc[rt][ct].w = 0.f;
        }
#pragma unroll
    for (int ks = 0; ks < 4; ++ks)
#pragma unroll
        for (int ct = 0; ct < 8; ++ct) {
            const unsigned* fp = &HpT[(ks * 8 + ct) * FS + lane * 8];
            uint4 a0 = *reinterpret_cast<const uint4*>(fp);
            uint4 a1 = *reinterpret_cast<const uint4*>(fp + 4);
            unsigned ww[8] = {a0.x, a0.y, a0.z, a0.w, a1.x, a1.y, a1.z, a1.w};
            bfrag bh, bl;
#pragma unroll
            for (int j = 0; j < 8; ++j) {
                bh[j] = us2bf((unsigned short)(ww[j] >> 16));
                bl[j] = us2bf((unsigned short)(ww[j] & 0xFFFFu));
            }
#pragma unroll
            for (int rt = 0; rt < 2; ++rt) {
                const int r = rt * 4 + ks;
                acc[rt][ct] = __builtin_amdgcn_mfma_f32_16x16x32_bf16(ah[r], bh, acc[rt][ct], 0, 0, 0);
                acc[rt][ct] = __builtin_amdgcn_mfma_f32_16x16x32_bf16(al[r], bh, acc[rt][ct], 0, 0, 0);
                acc[rt][ct] = __builtin_amdgcn_mfma_f32_16x16x32_bf16(ah[r], bl, acc[rt][ct], 0, 0, 0);
                acc[rt][ct] = __builtin_amdgcn_mfma_f32_16x16x32_bf16(al[r], bl, acc[rt][ct], 0, 0, 0);
            }
        }
    __syncthreads();   // all frag reads done; rsl ready -> HpT reusable for H0'

    // ---- epilogue: H0' = rs*H0, pack hi|lo dword, b128 stores feature-major ----
#pragma unroll
    for (int rt = 0; rt < 2; ++rt) {
        const int mb = m0 + rt * 16 + quad * 4;
        f4 rs4 = *reinterpret_cast<const f4*>(&rsl[mb]);
#pragma unroll
        for (int ct = 0; ct < 8; ++ct) {
            uint4 st;
            unsigned pw[4];
#pragma unroll
            for (int reg = 0; reg < 4; ++reg) {
                float v = acc[rt][ct][reg] * rs4[reg];
                __bf16 hb = (__bf16)v;
                __bf16 lb = (__bf16)(v - (float)hb);
                pw[reg] = ((unsigned)bf2us(hb) << 16) | (unsigned)bf2us(lb);
            }
            st.x = pw[0]; st.y = pw[1]; st.z = pw[2]; st.w = pw[3];
            *reinterpret_cast<uint4*>(&HpT[(ct * 16 + n16) * HS + mb]) = st;
        }
    }
    __syncthreads();

    // ---- conv1 aggregation via MFMA: agg = (Adj+I) @ H0'(hi+lo) ----
    f4 hacc[2][8];
#pragma unroll
    for (int mt = 0; mt < 2; ++mt)
#pragma unroll
        for (int ct = 0; ct < 8; ++ct) {
            hacc[mt][ct].x = 0.f; hacc[mt][ct].y = 0.f;
            hacc[mt][ct].z = 0.f; hacc[mt][ct].w = 0.f;
        }
#pragma unroll
    for (int ks = 0; ks < 4; ++ks) {
        bfrag af[2];
#pragma unroll
        for (int mt = 0; mt < 2; ++mt) {
            unsigned w = AdjN[(m0 + mt * 16 + n16) * AS + ks * 4 + quad];
#pragma unroll
            for (int j = 0; j < 8; ++j)
                af[mt][j] = (__bf16)(float)((w >> (4 * j)) & 15u);
        }
#pragma unroll
        for (int ct = 0; ct < 8; ++ct) {
            const unsigned* bp = &HpT[(ct * 16 + n16) * HS + ks * 32 + quad * 8];
            uint4 w0 = *reinterpret_cast<const uint4*>(bp);
            uint4 w1 = *reinterpret_cast<const uint4*>(bp + 4);
            unsigned ww[8] = {w0.x, w0.y, w0.z, w0.w, w1.x, w1.y, w1.z, w1.w};
            bfrag bh, bl;
#pragma unroll
            for (int j = 0; j < 8; ++j) {
                bh[j] = us2bf((unsigned short)(ww[j] >> 16));
                bl[j] = us2bf((unsigned short)(ww[j] & 0xFFFFu));
            }
#pragma unroll
            for (int mt = 0; mt < 2; ++mt) {
                hacc[mt][ct] = __builtin_amdgcn_mfma_f32_16x16x32_bf16(af[mt], bh, hacc[mt][ct], 0, 0, 0);
                hacc[mt][ct] = __builtin_amdgcn_mfma_f32_16x16x32_bf16(af[mt], bl, hacc[mt][ct], 0, 0, 0);
            }
        }
    }

    // epilogue in regs: h = relu(rs*agg + b1)   (h stays in registers)
    f4 rsm[2];
#pragma unroll
    for (int mt = 0; mt < 2; ++mt)
        rsm[mt] = *reinterpret_cast<const f4*>(&rsl[m0 + mt * 16 + quad * 4]);
#pragma unroll
    for (int mt = 0; mt < 2; ++mt)
#pragma unroll
        for (int ct = 0; ct < 8; ++ct)
#pragma unroll
            for (int reg = 0; reg < 4; ++reg)
                hacc[mt][ct][reg] = fmaxf(hacc[mt][ct][reg] * rsm[mt][reg] + b1v[ct], 0.f);

    // ---- spl' = rs * (h @ Ws): per-row dot, shfl_xor reduce over n-group ----
    {
        float dot[2][4];
#pragma unroll
        for (int mt = 0; mt < 2; ++mt)
#pragma unroll
            for (int reg = 0; reg < 4; ++reg) dot[mt][reg] = 0.f;
#pragma unroll
        for (int ct = 0; ct < 8; ++ct)
#pragma unroll
            for (int mt = 0; mt < 2; ++mt)
#pragma unroll
                for (int reg = 0; reg < 4; ++reg)
                    dot[mt][reg] += hacc[mt][ct][reg] * wsv[ct];
#pragma unroll
        for (int d = 1; d < 16; d <<= 1)
#pragma unroll
            for (int mt = 0; mt < 2; ++mt)
#pragma unroll
                for (int reg = 0; reg < 4; ++reg)
                    dot[mt][reg] += __shfl_xor(dot[mt][reg], d, 64);
        if (n16 == 0) {
#pragma unroll
            for (int mt = 0; mt < 2; ++mt)
#pragma unroll
                for (int reg = 0; reg < 4; ++reg)
                    spl[m0 + mt * 16 + quad * 4 + reg] = rsm[mt][reg] * dot[mt][reg];
        }
    }
    __syncthreads();

    // ---- score = rs * ((Adj+I) @ spl') + bs  via dense nibble rows ----
    if (t < NPG) {
        const unsigned* row = &AdjN[t * AS];
        float sc = 0.f;
#pragma unroll
        for (int w = 0; w < 16; ++w) {
            unsigned u = row[w];
            const float* sp = &spl[w * 8];
            sc += (float)(u & 15u)         * sp[0] + (float)((u >> 4)  & 15u) * sp[1]
                + (float)((u >> 8)  & 15u) * sp[2] + (float)((u >> 12) & 15u) * sp[3]
                + (float)((u >> 16) & 15u) * sp[4] + (float)((u >> 20) & 15u) * sp[5]
                + (float)((u >> 24) & 15u) * sp[6] + (float)(u >> 28)         * sp[7];
        }
        scl[t] = rsl[t] * sc + bsv;
    }
    __syncthreads();

    // ---- top-K by exact rank (stable), fully unrolled float4 broadcasts ----
    if (t < NPG) {
        float v = scl[t];
        int rank = 0;
#pragma unroll
        for (int j4 = 0; j4 < 32; ++j4) {
            float4 u = *reinterpret_cast<const float4*>(&scl[j4 * 4]);
            const int jb = j4 * 4;
            rank += (u.x > v || (u.x == v && jb     < t)) ? 1 : 0;
            rank += (u.y > v || (u.y == v && jb + 1 < t)) ? 1 : 0;
            rank += (u.z > v || (u.z == v && jb + 2 < t)) ? 1 : 0;
            rank += (u.w > v || (u.w == v && jb + 3 < t)) ? 1 : 0;
        }
        wgt[t] = (rank < KSEL) ? tanhf(v) * (1.0f / KSEL) : 0.f;
    }
    __syncthreads();

    // ---- pooled[c] = sum_m wgt[m]*h[m][c] from registers; shfl over quads ----
    {
        float p[8];
        f4 wm[2];
#pragma unroll
        for (int mt = 0; mt < 2; ++mt)
            wm[mt] = *reinterpret_cast<const f4*>(&wgt[m0 + mt * 16 + quad * 4]);
#pragma unroll
        for (int ct = 0; ct < 8; ++ct) {
            float s = 0.f;
#pragma unroll
            for (int mt = 0; mt < 2; ++mt)
#pragma unroll
                for (int reg = 0; reg < 4; ++reg)
                    s += wm[mt][reg] * hacc[mt][ct][reg];
            p[ct] = s;
        }
#pragma unroll
        for (int d = 16; d < 64; d <<= 1)
#pragma unroll
            for (int ct = 0; ct < 8; ++ct)
                p[ct] += __shfl_xor(p[ct], d, 64);
        if (quad == 0) {
#pragma unroll
            for (int ct = 0; ct < 8; ++ct)
                pp[wv * HID + ct * 16 + n16] = p[ct];
        }
    }
    __syncthreads();
    if (t < NPG)
        scl[t] = pp[t] + pp[HID + t] + pp[2 * HID + t] + pp[3 * HID + t];  // pooled
    __syncthreads();

    // ---- out = pooled @ Wlin + blin (split-k over 2 halves, L2-hot global) ----
    {
        const int c = t & 127, hf = t >> 7;
        float s = 0.f;
#pragma unroll 8
        for (int k = hf * 64; k < hf * 64 + 64; ++k)
            s += scl[k] * Wlin[k * HID + c];
        pp[t] = s;
    }
    __syncthreads();
    if (t < NPG)
        out[(long)g * HID + t] = pp[t] + pp[t + 128] + blin[t];
}

extern "C" void kernel_launch(void* const* d_in, const int* in_sizes, int n_in,
                              void* d_out, int out_size, void* d_ws, size_t ws_size,
                              hipStream_t stream) {
    const float* x    = (const float*)d_in[0];
    const int*   ei   = (const int*)  d_in[1];
    const float* W1   = (const float*)d_in[3];
    const float* b1   = (const float*)d_in[4];
    const float* Ws   = (const float*)d_in[5];
    const float* bs   = (const float*)d_in[6];
    const float* Wlin = (const float*)d_in[7];
    const float* blin = (const float*)d_in[8];
    float* out = (float*)d_out;

    const int E = in_sizes[1] / 2;          // 1048576
    const int nnodes = in_sizes[0] / HID;   // 65536
    const int B = nnodes / NPG;             // 512
    const int epg = E / B;                  // 2048

    sagpool_fused<<<B, NT, 0, stream>>>(x, ei, ei + E, W1, b1, Ws, bs,
                                        Wlin, blin, out, epg);
}